// Round 1
// baseline (324.191 us; speedup 1.0000x reference)
//
#include <hip/hip_runtime.h>

// Problem constants (from setup_inputs): B=16, S=2048, H=1024, C=4 kept rfft coeffs.
// Math: keeping rfft coeffs k=0..3 (ortho) == rank-7 projection per (b,h) column:
//   a0 = sum_s x ; ak = sum_s x cos(2pi k s/S) ; bk = sum_s x sin(2pi k s/S), k=1..3
//   low[s] = (a0 + 2*sum_k(ak*cos + bk*sin)) / S
// Then seq_emb_fft + input = (1+beta^2)*x + (1-beta^2)*low ; LayerNorm over H.

constexpr int Sc = 2048;
constexpr int Hc = 1024;
constexpr int SCHUNKS = 32;            // s-chunks in pass 1 -> 32*B blocks
constexpr int SCHUNK = Sc / SCHUNKS;   // 64 rows per block
constexpr float TWO_PI_OVER_S = 6.283185307179586f / (float)Sc;

__device__ __forceinline__ void sincos7(int s, float w[7]) {
    float sn1, cs1;
    sincosf(TWO_PI_OVER_S * (float)s, &sn1, &cs1);
    const float cs2 = fmaf(2.f * cs1, cs1, -1.f);
    const float sn2 = 2.f * sn1 * cs1;
    const float cs3 = cs1 * cs2 - sn1 * sn2;
    const float sn3 = sn1 * cs2 + cs1 * sn2;
    w[0] = 1.f; w[1] = cs1; w[2] = sn1; w[3] = cs2; w[4] = sn2; w[5] = cs3; w[6] = sn3;
}

// Pass 1: per (b,h) compute the 7 projection sums over s.
// coef layout: [b][j][h], j in 0..6 -> coef[(b*7 + j)*Hc + h]
__global__ __launch_bounds__(256) void freq_coeff_kernel(
    const float* __restrict__ x, float* __restrict__ coef) {
    const int tid = threadIdx.x;           // 256 threads, float4 each -> all H
    const int b   = blockIdx.y;
    const int s0  = blockIdx.x * SCHUNK;

    const float4* __restrict__ xb =
        reinterpret_cast<const float4*>(x) + (size_t)b * Sc * (Hc / 4) + tid;

    float acc[7][4];
#pragma unroll
    for (int j = 0; j < 7; ++j)
#pragma unroll
        for (int e = 0; e < 4; ++e) acc[j][e] = 0.f;

    for (int si = 0; si < SCHUNK; ++si) {
        const int s = s0 + si;
        float w[7];
        sincos7(s, w);
        const float4 v = xb[(size_t)s * (Hc / 4)];
        const float vv[4] = {v.x, v.y, v.z, v.w};
#pragma unroll
        for (int j = 0; j < 7; ++j)
#pragma unroll
            for (int e = 0; e < 4; ++e)
                acc[j][e] = fmaf(w[j], vv[e], acc[j][e]);
    }

    const int h = tid * 4;
#pragma unroll
    for (int j = 0; j < 7; ++j)
#pragma unroll
        for (int e = 0; e < 4; ++e)
            atomicAdd(&coef[((size_t)b * 7 + j) * Hc + h + e], acc[j][e]);
}

// Pass 2: per (b,s) row -> rebuild low_pass from coeffs, fuse, LayerNorm over H.
__global__ __launch_bounds__(256) void freq_ln_kernel(
    const float* __restrict__ x, const float* __restrict__ coef,
    const float* __restrict__ sqb, const float* __restrict__ gamma,
    const float* __restrict__ lbeta, float* __restrict__ out) {
    const int row = blockIdx.x;            // b*Sc + s
    const int b   = row >> 11;             // Sc = 2048
    const int s   = row & (Sc - 1);
    const int tid = threadIdx.x;

    float w[7];
    sincos7(s, w);

    const float4 xv = reinterpret_cast<const float4*>(x)[(size_t)row * (Hc / 4) + tid];
    const float4* cf = reinterpret_cast<const float4*>(coef) + (size_t)b * 7 * (Hc / 4) + tid;
    float4 cj[7];
#pragma unroll
    for (int j = 0; j < 7; ++j) cj[j] = cf[(size_t)j * (Hc / 4)];
    const float4 sb = reinterpret_cast<const float4*>(sqb)[tid];

    const float xx[4] = {xv.x, xv.y, xv.z, xv.w};
    const float bb[4] = {sb.x, sb.y, sb.z, sb.w};
    float y[4];
#pragma unroll
    for (int e = 0; e < 4; ++e) {
        const float c[7] = {
            e == 0 ? cj[0].x : e == 1 ? cj[0].y : e == 2 ? cj[0].z : cj[0].w,
            e == 0 ? cj[1].x : e == 1 ? cj[1].y : e == 2 ? cj[1].z : cj[1].w,
            e == 0 ? cj[2].x : e == 1 ? cj[2].y : e == 2 ? cj[2].z : cj[2].w,
            e == 0 ? cj[3].x : e == 1 ? cj[3].y : e == 2 ? cj[3].z : cj[3].w,
            e == 0 ? cj[4].x : e == 1 ? cj[4].y : e == 2 ? cj[4].z : cj[4].w,
            e == 0 ? cj[5].x : e == 1 ? cj[5].y : e == 2 ? cj[5].z : cj[5].w,
            e == 0 ? cj[6].x : e == 1 ? cj[6].y : e == 2 ? cj[6].z : cj[6].w};
        float lp = c[0];
#pragma unroll
        for (int j = 1; j < 7; ++j) lp = fmaf(2.f * c[j], w[j], lp);
        lp *= (1.f / (float)Sc);
        const float t = bb[e] * bb[e];
        y[e] = fmaf(1.f + t, xx[e], (1.f - t) * lp);
    }

    // block reduction: mean then variance (y stays in registers)
    __shared__ float sm1[4], sm2[4];
    const int lane = tid & 63, wv = tid >> 6;

    float sum = y[0] + y[1] + y[2] + y[3];
#pragma unroll
    for (int off = 32; off > 0; off >>= 1) sum += __shfl_down(sum, off, 64);
    if (lane == 0) sm1[wv] = sum;
    __syncthreads();
    const float mean = (sm1[0] + sm1[1] + sm1[2] + sm1[3]) * (1.f / (float)Hc);

    float vs = 0.f;
#pragma unroll
    for (int e = 0; e < 4; ++e) { const float d = y[e] - mean; vs = fmaf(d, d, vs); }
#pragma unroll
    for (int off = 32; off > 0; off >>= 1) vs += __shfl_down(vs, off, 64);
    if (lane == 0) sm2[wv] = vs;
    __syncthreads();
    const float var = (sm2[0] + sm2[1] + sm2[2] + sm2[3]) * (1.f / (float)Hc);
    const float inv = rsqrtf(var + 1e-12f);

    const float4 g4 = reinterpret_cast<const float4*>(gamma)[tid];
    const float4 be4 = reinterpret_cast<const float4*>(lbeta)[tid];
    const float gg[4] = {g4.x, g4.y, g4.z, g4.w};
    const float be[4] = {be4.x, be4.y, be4.z, be4.w};
    float4 o;
    o.x = fmaf((y[0] - mean) * inv, gg[0], be[0]);
    o.y = fmaf((y[1] - mean) * inv, gg[1], be[1]);
    o.z = fmaf((y[2] - mean) * inv, gg[2], be[2]);
    o.w = fmaf((y[3] - mean) * inv, gg[3], be[3]);
    reinterpret_cast<float4*>(out)[(size_t)row * (Hc / 4) + tid] = o;
}

extern "C" void kernel_launch(void* const* d_in, const int* in_sizes, int n_in,
                              void* d_out, int out_size, void* d_ws, size_t ws_size,
                              hipStream_t stream) {
    const float* x     = (const float*)d_in[0];   // [B,S,H] f32
    const float* sqb   = (const float*)d_in[1];   // [H]
    const float* gamma = (const float*)d_in[2];   // [H]
    const float* lbeta = (const float*)d_in[3];   // [H]
    float* out = (float*)d_out;
    float* coef = (float*)d_ws;                   // [B][7][H] f32 = 448 KiB

    const int B = in_sizes[0] / (Sc * Hc);        // 16

    hipMemsetAsync(coef, 0, (size_t)B * 7 * Hc * sizeof(float), stream);

    dim3 g1(SCHUNKS, B);
    freq_coeff_kernel<<<g1, 256, 0, stream>>>(x, coef);

    freq_ln_kernel<<<B * Sc, 256, 0, stream>>>(x, coef, sqb, gamma, lbeta, out);
}

// Round 3
// 276.512 us; speedup vs baseline: 1.1724x; 1.1724x over previous
//
#include <hip/hip_runtime.h>

// B=16, S=2048, H=1024, C=4 kept rfft coeffs (ortho) == rank-7 projection:
//   a0 = sum_s x ; ak = sum_s x cos(2pi k s/S) ; bk = sum_s x sin(2pi k s/S), k=1..3
//   low[s] = (a0 + 2*sum_k(ak*cos + bk*sin)) / S
//   out = LayerNorm_H( (1+beta^2)*x + (1-beta^2)*low )
//
// Pass 1: partial sums per s-chunk (no atomics) -> coefp[chunk][b][7][H]
// Pass 1.5: reduce chunks -> coef[b][7][H]
// Pass 2: 4 rows/block, rebuild low, fuse, single-pass LayerNorm (sum,sumsq)

constexpr int Sc = 2048;
constexpr int Hc = 1024;
constexpr float TWO_PI_OVER_S = 6.283185307179586f / (float)Sc;

typedef float nfloat4 __attribute__((ext_vector_type(4)));  // native vec for nontemporal builtin

__device__ __forceinline__ void sincos7(int s, float w[7]) {
    float sn1, cs1;
    sincosf(TWO_PI_OVER_S * (float)s, &sn1, &cs1);
    const float cs2 = fmaf(2.f * cs1, cs1, -1.f);
    const float sn2 = 2.f * sn1 * cs1;
    const float cs3 = cs1 * cs2 - sn1 * sn2;
    const float sn3 = sn1 * cs2 + cs1 * sn2;
    w[0] = 1.f; w[1] = cs1; w[2] = sn1; w[3] = cs2; w[4] = sn2; w[5] = cs3; w[6] = sn3;
}

// ---------------- Pass 1: partial projection sums, no atomics ----------------
__global__ __launch_bounds__(256) void freq_coeff_partial(
    const float* __restrict__ x, float* __restrict__ coefp,
    int B, int schunk) {
    const int tid   = threadIdx.x;        // 256 threads x float4 = all H
    const int b     = blockIdx.y;
    const int chunk = blockIdx.x;
    const int s0    = chunk * schunk;

    const float4* __restrict__ xb =
        reinterpret_cast<const float4*>(x) + (size_t)b * Sc * (Hc / 4) + tid;

    float acc[7][4];
#pragma unroll
    for (int j = 0; j < 7; ++j)
#pragma unroll
        for (int e = 0; e < 4; ++e) acc[j][e] = 0.f;

    for (int si = 0; si < schunk; si += 4) {
        float4 v[4];
#pragma unroll
        for (int r = 0; r < 4; ++r)
            v[r] = xb[(size_t)(s0 + si + r) * (Hc / 4)];
#pragma unroll
        for (int r = 0; r < 4; ++r) {
            float w[7];
            sincos7(s0 + si + r, w);
            const float vv[4] = {v[r].x, v[r].y, v[r].z, v[r].w};
#pragma unroll
            for (int j = 0; j < 7; ++j)
#pragma unroll
                for (int e = 0; e < 4; ++e)
                    acc[j][e] = fmaf(w[j], vv[e], acc[j][e]);
        }
    }

    float4* cp = reinterpret_cast<float4*>(coefp) +
                 ((size_t)chunk * B + b) * 7 * (Hc / 4) + tid;
#pragma unroll
    for (int j = 0; j < 7; ++j) {
        float4 o = {acc[j][0], acc[j][1], acc[j][2], acc[j][3]};
        cp[(size_t)j * (Hc / 4)] = o;
    }
}

// ---------------- Pass 1.5: reduce chunk partials ----------------
__global__ __launch_bounds__(256) void coeff_reduce(
    const float* __restrict__ coefp, float* __restrict__ coef,
    int CK, int n4) {
    const int i = blockIdx.x * 256 + threadIdx.x;   // float4 index into [B*7*H]
    if (i >= n4) return;
    const float4* __restrict__ p = reinterpret_cast<const float4*>(coefp) + i;
    float4 s = {0.f, 0.f, 0.f, 0.f};
    for (int c = 0; c < CK; ++c) {
        const float4 v = p[(size_t)c * n4];
        s.x += v.x; s.y += v.y; s.z += v.z; s.w += v.w;
    }
    reinterpret_cast<float4*>(coef)[i] = s;
}

// ---------------- Pass 2: 4 rows per block, fused LN ----------------
__global__ __launch_bounds__(256) void freq_ln_kernel(
    const float* __restrict__ x, const float* __restrict__ coef,
    const float* __restrict__ sqb, const float* __restrict__ gamma,
    const float* __restrict__ lbeta, float* __restrict__ out) {
    const int tid = threadIdx.x;
    const int b   = blockIdx.y;
    const int s0  = blockIdx.x * 4;
    const size_t rowBase = ((size_t)b * Sc + s0) * (Hc / 4) + tid;

    // params (L2/L3 resident)
    const float4 sb4 = reinterpret_cast<const float4*>(sqb)[tid];
    const float4 g4  = reinterpret_cast<const float4*>(gamma)[tid];
    const float4 be4 = reinterpret_cast<const float4*>(lbeta)[tid];
    const float bb[4] = {sb4.x, sb4.y, sb4.z, sb4.w};
    const float gg[4] = {g4.x, g4.y, g4.z, g4.w};
    const float be[4] = {be4.x, be4.y, be4.z, be4.w};
    float ap[4], am[4];
#pragma unroll
    for (int e = 0; e < 4; ++e) {
        const float t = bb[e] * bb[e];
        ap[e] = 1.f + t;
        am[e] = (1.f - t) * (1.f / (float)Sc);
    }

    // coefficients for this b (reused across 4 rows)
    const float4* __restrict__ CF =
        reinterpret_cast<const float4*>(coef) + (size_t)b * 7 * (Hc / 4) + tid;
    float cf[7][4];
#pragma unroll
    for (int j = 0; j < 7; ++j) {
        const float4 t = CF[(size_t)j * (Hc / 4)];
        cf[j][0] = t.x; cf[j][1] = t.y; cf[j][2] = t.z; cf[j][3] = t.w;
    }

    // x rows
    float4 xv[4];
#pragma unroll
    for (int r = 0; r < 4; ++r)
        xv[r] = reinterpret_cast<const float4*>(x)[rowBase + (size_t)r * (Hc / 4)];

    float y[4][4], s1[4], s2[4];
#pragma unroll
    for (int r = 0; r < 4; ++r) {
        float w[7];
        sincos7(s0 + r, w);
#pragma unroll
        for (int j = 1; j < 7; ++j) w[j] *= 2.f;
        const float xx[4] = {xv[r].x, xv[r].y, xv[r].z, xv[r].w};
        s1[r] = 0.f; s2[r] = 0.f;
#pragma unroll
        for (int e = 0; e < 4; ++e) {
            float lp = cf[0][e];
#pragma unroll
            for (int j = 1; j < 7; ++j) lp = fmaf(cf[j][e], w[j], lp);
            const float yy = fmaf(ap[e], xx[e], am[e] * lp);
            y[r][e] = yy;
            s1[r] += yy;
            s2[r] = fmaf(yy, yy, s2[r]);
        }
    }

    // fused block reduction of (sum, sumsq) x 4 rows
    const int lane = tid & 63, wv = tid >> 6;
#pragma unroll
    for (int off = 32; off > 0; off >>= 1) {
#pragma unroll
        for (int r = 0; r < 4; ++r) {
            s1[r] += __shfl_down(s1[r], off, 64);
            s2[r] += __shfl_down(s2[r], off, 64);
        }
    }
    __shared__ float sm[4][8];
    if (lane == 0) {
#pragma unroll
        for (int r = 0; r < 4; ++r) { sm[wv][r] = s1[r]; sm[wv][4 + r] = s2[r]; }
    }
    __syncthreads();

#pragma unroll
    for (int r = 0; r < 4; ++r) {
        const float m  = (sm[0][r] + sm[1][r] + sm[2][r] + sm[3][r]) * (1.f / (float)Hc);
        const float q  = (sm[0][4 + r] + sm[1][4 + r] + sm[2][4 + r] + sm[3][4 + r]) * (1.f / (float)Hc);
        const float inv = rsqrtf(fmaf(-m, m, q) + 1e-12f);
        nfloat4 o;
        o.x = fmaf((y[r][0] - m) * inv, gg[0], be[0]);
        o.y = fmaf((y[r][1] - m) * inv, gg[1], be[1]);
        o.z = fmaf((y[r][2] - m) * inv, gg[2], be[2]);
        o.w = fmaf((y[r][3] - m) * inv, gg[3], be[3]);
        __builtin_nontemporal_store(o, reinterpret_cast<nfloat4*>(out) + rowBase + (size_t)r * (Hc / 4));
    }
}

extern "C" void kernel_launch(void* const* d_in, const int* in_sizes, int n_in,
                              void* d_out, int out_size, void* d_ws, size_t ws_size,
                              hipStream_t stream) {
    const float* x     = (const float*)d_in[0];   // [B,S,H] f32
    const float* sqb   = (const float*)d_in[1];   // [H]
    const float* gamma = (const float*)d_in[2];   // [H]
    const float* lbeta = (const float*)d_in[3];   // [H]
    float* out = (float*)d_out;

    const int B = in_sizes[0] / (Sc * Hc);        // 16
    const size_t coefElems = (size_t)B * 7 * Hc;  // 114688
    const size_t coefBytes = coefElems * sizeof(float);

    // pick chunk count CK so (CK partials + 1 final) fit in ws; CK==1 needs no reduce
    int CK = 64;
    while (CK > 1 && (size_t)(CK + 1) * coefBytes > ws_size) CK >>= 1;

    float* coefp = (float*)d_ws;                          // [CK][B][7][H]
    float* coef  = (CK == 1) ? coefp : coefp + CK * coefElems;

    const int schunk = Sc / CK;                           // rows per pass-1 block
    dim3 g1(CK, B);
    freq_coeff_partial<<<g1, 256, 0, stream>>>(x, coefp, B, schunk);

    if (CK > 1) {
        const int n4 = (int)(coefElems / 4);              // 28672 float4
        coeff_reduce<<<(n4 + 255) / 256, 256, 0, stream>>>(coefp, coef, CK, n4);
    }

    dim3 g2(Sc / 4, B);
    freq_ln_kernel<<<g2, 256, 0, stream>>>(x, coef, sqb, gamma, lbeta, out);
}